// Round 11
// baseline (214.038 us; speedup 1.0000x reference)
//
#include <hip/hip_runtime.h>

// Model dims (fixed by the problem)
#define TT    128
#define CC    64
#define HH    4
#define SS    16
#define D4    256     // 4*C
#define HID_  256
#define VV    32000
#define NPE_  4
#define RR    256     // B*T
#define LOG2E 1.44269504f

__device__ __forceinline__ float wred_sum(float v) {
#pragma unroll
    for (int off = 32; off; off >>= 1) v += __shfl_xor(v, off, 64);
    return v;
}
__device__ __forceinline__ float wred_max(float v) {
#pragma unroll
    for (int off = 32; off; off >>= 1) v = fmaxf(v, __shfl_xor(v, off, 64));
    return v;
}
__device__ __forceinline__ float sigm(float x) {
    return __builtin_amdgcn_rcpf(1.f + exp2f(-x * LOG2E));
}
__device__ __forceinline__ float sigm2(float t) {   // input pre-scaled by log2e
    return __builtin_amdgcn_rcpf(1.f + exp2f(-t));
}

// ============ embed + all positional embeddings (one launch) ============
__global__ void k_embed_pos(const int* __restrict__ idx, const float* __restrict__ tok,
                            const float* __restrict__ pe_tab, const float* __restrict__ W1,
                            const float* __restrict__ b1, const float* __restrict__ W2,
                            const float* __restrict__ b2, const float* __restrict__ g,
                            const float* __restrict__ bb,
                            float* __restrict__ x, float* __restrict__ pos) {
    int blk = blockIdx.x, c = threadIdx.x;
    if (blk >= 512) {
        int r = blk - 512;
        x[r * CC + c] = tok[idx[r] * CC + c];
        return;
    }
    int p = blk >> 7, t = blk & 127;
    __shared__ float s_pe[CC], s_h[CC];
    s_pe[c] = pe_tab[(p * TT + t) * CC + c];
    __syncthreads();
    const float* w1 = W1 + p * CC * CC;
    float a = b1[p * CC + c];
    for (int k = 0; k < CC; k++) a += s_pe[k] * w1[k * CC + c];
    s_h[c] = sigm(a);
    __syncthreads();
    const float* w2 = W2 + p * CC * CC;
    float o = b2[p * CC + c];
    for (int k = 0; k < CC; k++) o += s_h[k] * w2[k * CC + c];
    float m = wred_sum(o) * (1.f / CC);
    float d = o - m;
    float var = wred_sum(d * d) * (1.f / CC);
    pos[(p * TT + t) * CC + c] =
        d * rsqrtf(var + 1e-5f) * g[p * CC + c] + bb[p * CC + c];
}

// ============ stage A: LN1 + K&Q proj + V, 4-row blocks ============
// 256 blocks: rq = blk&63 (4 rows), h = blk>>6. K written transposed.
__global__ void __launch_bounds__(256) k_stageA(
    const float* __restrict__ x, const float* __restrict__ pos_p,
    const float* __restrict__ ln1g, const float* __restrict__ ln1b,
    const float* __restrict__ attW1, const float* __restrict__ ab1,
    const float* __restrict__ valW,
    float* __restrict__ KpT, float* __restrict__ Qp, float* __restrict__ v) {
    int blk = blockIdx.x, tid = threadIdx.x;
    int lane = tid & 63, wv = tid >> 6;
    int rq = blk & 63, h = blk >> 6;
    int r0 = rq * 4;
    __shared__ __align__(16) float x1T[128][4];   // [c][row]
    {   // wave wv handles row r0+wv: pos into cols 0..63, LN1(x) into 64..127
        int r = r0 + wv, t = r & 127;
        float xv = x[r * CC + lane];
        float m = wred_sum(xv) * (1.f / CC);
        float d = xv - m;
        float var = wred_sum(d * d) * (1.f / CC);
        x1T[64 + lane][wv] = d * rsqrtf(var + 1e-5f) * ln1g[lane] + ln1b[lane];
        x1T[lane][wv] = pos_p[t * CC + lane];
    }
    __syncthreads();
    int d = tid;
    const float* wk = attW1 + (size_t)(h * D4) * D4 + d;          // K rows 0..127
    const float* wq = attW1 + (size_t)(h * D4 + 128) * D4 + d;    // Q rows 128..255
    float k0 = 0, k1 = 0, k2 = 0, k3 = 0, q0 = 0, q1 = 0, q2 = 0, q3 = 0;
#pragma unroll 4
    for (int c = 0; c < 128; ++c) {
        float4 xr = *(const float4*)&x1T[c][0];   // one b128 broadcast
        float wkv = wk[(size_t)c * D4];
        float wqv = wq[(size_t)c * D4];
        k0 += xr.x * wkv; k1 += xr.y * wkv; k2 += xr.z * wkv; k3 += xr.w * wkv;
        q0 += xr.x * wqv; q1 += xr.y * wqv; q2 += xr.z * wqv; q3 += xr.w * wqv;
    }
    float badd = ab1[h * D4 + d];                 // fold b1 into K
    float4 ko = {(k0 + badd) * LOG2E, (k1 + badd) * LOG2E,
                 (k2 + badd) * LOG2E, (k3 + badd) * LOG2E};
    *(float4*)(KpT + (size_t)(h * D4 + d) * RR + r0) = ko;   // transposed K
    Qp[(h * RR + r0 + 0) * D4 + d] = q0 * LOG2E;
    Qp[(h * RR + r0 + 1) * D4 + d] = q1 * LOG2E;
    Qp[(h * RR + r0 + 2) * D4 + d] = q2 * LOG2E;
    Qp[(h * RR + r0 + 3) * D4 + d] = q3 * LOG2E;
    if (tid < 64) {   // V: 4 rows x 16 s
        int rr = tid >> 4, s = tid & 15;
        float a = 0.f;
        for (int k = 0; k < CC; ++k) a += x1T[64 + k][rr] * valW[(h * CC + k) * SS + s];
        v[(h * RR + r0 + rr) * SS + s] = a;
    }
}

// ============ attention: block = (4 rows, head); j-per-lane, no shuffles ======
__global__ void __launch_bounds__(256) k_attn(
    const float* __restrict__ KpT, const float* __restrict__ Qp,
    const float* __restrict__ v,
    const float* __restrict__ aw2, const float* __restrict__ ab2,
    float* __restrict__ o) {
    int blk = blockIdx.x;
    int rq = blk & 63, h = blk >> 6;
    int r0 = rq * 4, bat = r0 >> 7;
    int ibase = r0 & 127, imax = ibase + 3;
    int tid = threadIdx.x;
    int j = tid & 127, dh = tid >> 7;
    int lane = tid & 63, wv = tid >> 6;
    __shared__ __align__(16) float qT[D4][4];     // [d][row]
    __shared__ float w2s[D4];
    __shared__ __align__(16) float ps[TT][2][4];  // [j][dh][row]
    __shared__ float sc[4][TT];
    __shared__ __align__(16) float vs[TT][SS];
    for (int e = tid; e < 4 * D4; e += 256) {
        int r = e >> 8, d = e & 255;
        qT[d][r] = Qp[(h * RR + r0 + r) * D4 + d];
    }
    w2s[tid] = aw2[h * D4 + tid] * 0.125f;        // fold C^-0.5
    {   // stage V tile (shared by the 4 rows)
        const float4* vb = (const float4*)(v + (size_t)(h * RR + bat * TT) * SS);
        float4* vd = (float4*)&vs[0][0];
        vd[tid] = vb[tid];
        vd[tid + 256] = vb[tid + 256];
    }
    __syncthreads();
    // scores: thread (j, dh) accumulates 4-row partials over its d-half
    if (j <= imax) {
        const float* kt = KpT + (size_t)(h * D4 + dh * 128) * RR + bat * TT + j;
        float a0 = 0, a1 = 0, a2 = 0, a3 = 0;
#pragma unroll 4
        for (int dd = 0; dd < 128; ++dd) {
            float kv = kt[(size_t)dd * RR];       // coalesced across j
            int d = dh * 128 + dd;
            float4 q4 = *(const float4*)&qT[d][0];
            float ww = w2s[d];
            a0 += sigm2(q4.x + kv) * ww;
            a1 += sigm2(q4.y + kv) * ww;
            a2 += sigm2(q4.z + kv) * ww;
            a3 += sigm2(q4.w + kv) * ww;
        }
        float4 av = {a0, a1, a2, a3};
        *(float4*)&ps[j][dh][0] = av;
    }
    __syncthreads();
    // softmax: wave wv = row wv
    {
        int iw = ibase + wv;
        float b2s = ab2[h] * 0.125f;
        float s0 = (lane <= iw) ? ps[lane][0][wv] + ps[lane][1][wv] + b2s : -1e30f;
        float s1 = (lane + 64 <= iw) ? ps[lane + 64][0][wv] + ps[lane + 64][1][wv] + b2s
                                     : -1e30f;
        float m = wred_max(fmaxf(s0, s1));
        float e0 = (lane <= iw) ? __expf(s0 - m) : 0.f;
        float e1 = (lane + 64 <= iw) ? __expf(s1 - m) : 0.f;
        float inv = __builtin_amdgcn_rcpf(wred_sum(e0 + e1));
        sc[wv][lane] = e0 * inv;
        sc[wv][lane + 64] = e1 * inv;
    }
    __syncthreads();
    // PV: wave wv = row wv; lane = (j4, s); 2-shuffle reduce
    {
        int iw = ibase + wv;
        int j4 = lane >> 4, s = lane & 15;
        float acc = 0.f;
        for (int jj = j4; jj <= iw; jj += 4) acc += sc[wv][jj] * vs[jj][s];
        acc += __shfl_xor(acc, 16, 64);
        acc += __shfl_xor(acc, 32, 64);
        if (j4 == 0) o[(r0 + wv) * CC + h * SS + s] = acc;
    }
}

// ============ post: proj + residual + LN2 + FF + residual + LN3 ============
__global__ void __launch_bounds__(256) k_post(
    float* __restrict__ x, const float* __restrict__ o,
    const float* __restrict__ projW, const float* __restrict__ projb,
    const float* __restrict__ g2, const float* __restrict__ b2,
    const float* __restrict__ fW1, const float* __restrict__ fb1,
    const float* __restrict__ fW2, const float* __restrict__ fb2,
    const float* __restrict__ g3, const float* __restrict__ b3) {
    int row = blockIdx.x, tid = threadIdx.x;
    __shared__ float o_s[CC], s_x[CC], s_h[HID_], red[4][CC];
    if (tid < CC) o_s[tid] = o[row * CC + tid];
    __syncthreads();
    {   // proj: 4-way k-split, 2 accumulators
        int c = tid & 63, q = tid >> 6;
        float a0 = 0.f, a1 = 0.f;
        int k0 = q * 16;
#pragma unroll
        for (int k = 0; k < 16; k += 2) {
            a0 += o_s[k0 + k] * projW[(k0 + k) * CC + c];
            a1 += o_s[k0 + k + 1] * projW[(k0 + k + 1) * CC + c];
        }
        red[q][c] = a0 + a1;
    }
    __syncthreads();
    float xv = 0.f;
    if (tid < CC) {
        xv = x[row * CC + tid] + projb[tid] +
             red[0][tid] + red[1][tid] + red[2][tid] + red[3][tid];
        float m = wred_sum(xv) * (1.f / CC);
        float d = xv - m;
        float var = wred_sum(d * d) * (1.f / CC);
        s_x[tid] = d * rsqrtf(var + 1e-5f) * g2[tid] + b2[tid];
    }
    __syncthreads();
    {   // FF1
        float a0 = fb1[tid], a1 = 0.f;
#pragma unroll
        for (int k = 0; k < CC; k += 2) {
            a0 += s_x[k] * fW1[k * HID_ + tid];
            a1 += s_x[k + 1] * fW1[(k + 1) * HID_ + tid];
        }
        s_h[tid] = sigm(a0 + a1);
    }
    __syncthreads();
    {   // FF2: 4-way k-split
        int c = tid & 63, q = tid >> 6;
        float a0 = 0.f, a1 = 0.f;
#pragma unroll
        for (int k = q * 64; k < q * 64 + 64; k += 2) {
            a0 += s_h[k] * fW2[k * CC + c];
            a1 += s_h[k + 1] * fW2[(k + 1) * CC + c];
        }
        red[q][c] = a0 + a1;
    }
    __syncthreads();
    if (tid < CC) {
        float f = fb2[tid] + red[0][tid] + red[1][tid] + red[2][tid] + red[3][tid];
        float x2 = xv + f;
        float m = wred_sum(x2) * (1.f / CC);
        float d = x2 - m;
        float var = wred_sum(d * d) * (1.f / CC);
        x[row * CC + tid] = d * rsqrtf(var + 1e-5f) * g3[tid] + b3[tid];
    }
}

// ============ lm_head: c-outer register GEMM ============
__global__ void __launch_bounds__(256, 4) k_lmhead(const float* __restrict__ x,
                                                   const float* __restrict__ lmW,
                                                   const float* __restrict__ lmb,
                                                   float* __restrict__ out) {
    int tid = threadIdx.x;
    int cp = tid & 127, rg = tid >> 7;
    int v2 = blockIdx.x * 256 + cp * 2;
    int r0 = blockIdx.y * 64;
    int rbase = rg * 32;
    __shared__ float xT[CC][68];            // transposed x tile, padded
    for (int e = tid; e < 64 * CC; e += 256) {
        int r = e >> 6, c = e & 63;
        xT[c][r] = x[(r0 + r) * CC + c];
    }
    __syncthreads();
    float2 bias = *(const float2*)(lmb + v2);
    float2 acc[32];
#pragma unroll
    for (int rr = 0; rr < 32; rr++) acc[rr] = bias;
    for (int c = 0; c < CC; ++c) {
        float2 w = *(const float2*)(lmW + (size_t)c * VV + v2);
#pragma unroll
        for (int q = 0; q < 8; ++q) {
            float4 xr = *(const float4*)&xT[c][rbase + q * 4];
            acc[q * 4 + 0].x += xr.x * w.x; acc[q * 4 + 0].y += xr.x * w.y;
            acc[q * 4 + 1].x += xr.y * w.x; acc[q * 4 + 1].y += xr.y * w.y;
            acc[q * 4 + 2].x += xr.z * w.x; acc[q * 4 + 2].y += xr.z * w.y;
            acc[q * 4 + 3].x += xr.w * w.x; acc[q * 4 + 3].y += xr.w * w.y;
        }
    }
#pragma unroll
    for (int rr = 0; rr < 32; rr++)
        *(float2*)(out + (size_t)(r0 + rbase + rr) * VV + v2) = acc[rr];
}

extern "C" void kernel_launch(void* const* d_in, const int* in_sizes, int n_in,
                              void* d_out, int out_size, void* d_ws, size_t ws_size,
                              hipStream_t stream) {
    const int*   idx   = (const int*)d_in[0];
    const float* tok   = (const float*)d_in[1];
    const float* petab = (const float*)d_in[2];
    const float* peW1  = (const float*)d_in[3];
    const float* peb1  = (const float*)d_in[4];
    const float* peW2  = (const float*)d_in[5];
    const float* peb2  = (const float*)d_in[6];
    const float* peg   = (const float*)d_in[7];
    const float* pebb  = (const float*)d_in[8];
    const float* ln1g  = (const float*)d_in[9];
    const float* ln1b  = (const float*)d_in[10];
    const float* attW1 = (const float*)d_in[11];
    const float* attb1 = (const float*)d_in[12];
    const float* attW2 = (const float*)d_in[13];
    const float* attb2 = (const float*)d_in[14];
    const float* valW  = (const float*)d_in[15];
    const float* projW = (const float*)d_in[16];
    const float* projb = (const float*)d_in[17];
    const float* ln2g  = (const float*)d_in[18];
    const float* ln2b  = (const float*)d_in[19];
    const float* ffW1  = (const float*)d_in[20];
    const float* ffb1  = (const float*)d_in[21];
    const float* ffW2  = (const float*)d_in[22];
    const float* ffb2  = (const float*)d_in[23];
    const float* ln3g  = (const float*)d_in[24];
    const float* ln3b  = (const float*)d_in[25];
    const float* lmW   = (const float*)d_in[26];
    const float* lmb   = (const float*)d_in[27];

    float* ws  = (float*)d_ws;
    float* x   = ws;                  // 16384
    float* pos = ws + 16384;          // 32768
    float* v   = ws + 49152;          // 16384
    float* o   = ws + 65536;          // 16384
    float* KpT = ws + 81920;          // 262144 (transposed, pre-scaled, +b1)
    float* Qp  = ws + 344064;         // 262144 (pre-scaled)

    k_embed_pos<<<768, CC, 0, stream>>>(idx, tok, petab, peW1, peb1, peW2, peb2,
                                        peg, pebb, x, pos);
    for (int p = 0; p < NPE_; p++) {
        k_stageA<<<256, 256, 0, stream>>>(x, pos + p * TT * CC, ln1g, ln1b,
                                          attW1, attb1, valW, KpT, Qp, v);
        k_attn<<<256, 256, 0, stream>>>(KpT, Qp, v, attW2, attb2, o);
        k_post<<<RR, 256, 0, stream>>>(x, o, projW, projb, ln2g, ln2b,
                                       ffW1, ffb1, ffW2, ffb2, ln3g, ln3b);
    }
    k_lmhead<<<dim3(125, 4), 256, 0, stream>>>(x, lmW, lmb, (float*)d_out);
}

// Round 12
// 196.730 us; speedup vs baseline: 1.0880x; 1.0880x over previous
//
#include <hip/hip_runtime.h>

// Model dims (fixed by the problem)
#define TT    128
#define CC    64
#define HH    4
#define SS    16
#define D4    256     // 4*C
#define HID_  256
#define VV    32000
#define NPE_  4
#define RR    256     // B*T
#define LOG2E 1.44269504f

__device__ __forceinline__ float wred_sum(float v) {
#pragma unroll
    for (int off = 32; off; off >>= 1) v += __shfl_xor(v, off, 64);
    return v;
}
__device__ __forceinline__ float wred_max(float v) {
#pragma unroll
    for (int off = 32; off; off >>= 1) v = fmaxf(v, __shfl_xor(v, off, 64));
    return v;
}
__device__ __forceinline__ float sigm(float x) {
    return __builtin_amdgcn_rcpf(1.f + exp2f(-x * LOG2E));
}
__device__ __forceinline__ float sigm2(float t) {   // input pre-scaled by log2e
    return __builtin_amdgcn_rcpf(1.f + exp2f(-t));
}

// ============ embed + all positional embeddings (one launch) ============
__global__ void k_embed_pos(const int* __restrict__ idx, const float* __restrict__ tok,
                            const float* __restrict__ pe_tab, const float* __restrict__ W1,
                            const float* __restrict__ b1, const float* __restrict__ W2,
                            const float* __restrict__ b2, const float* __restrict__ g,
                            const float* __restrict__ bb,
                            float* __restrict__ x, float* __restrict__ pos) {
    int blk = blockIdx.x, c = threadIdx.x;
    if (blk >= 512) {
        int r = blk - 512;
        x[r * CC + c] = tok[idx[r] * CC + c];
        return;
    }
    int p = blk >> 7, t = blk & 127;
    __shared__ float s_pe[CC], s_h[CC];
    s_pe[c] = pe_tab[(p * TT + t) * CC + c];
    __syncthreads();
    const float* w1 = W1 + p * CC * CC;
    float a = b1[p * CC + c];
    for (int k = 0; k < CC; k++) a += s_pe[k] * w1[k * CC + c];
    s_h[c] = sigm(a);
    __syncthreads();
    const float* w2 = W2 + p * CC * CC;
    float o = b2[p * CC + c];
    for (int k = 0; k < CC; k++) o += s_h[k] * w2[k * CC + c];
    float m = wred_sum(o) * (1.f / CC);
    float d = o - m;
    float var = wred_sum(d * d) * (1.f / CC);
    pos[(p * TT + t) * CC + c] =
        d * rsqrtf(var + 1e-5f) * g[p * CC + c] + bb[p * CC + c];
}

// ============ stage A: LN1 + K/Q proj (+V on kq==0 blocks) — R10 proven ======
__global__ void __launch_bounds__(256) k_stageA(
    const float* __restrict__ x, const float* __restrict__ pos_p,
    const float* __restrict__ ln1g, const float* __restrict__ ln1b,
    const float* __restrict__ attW1, const float* __restrict__ ab1,
    const float* __restrict__ valW,
    float* __restrict__ Kp, float* __restrict__ Qp, float* __restrict__ v) {
    int blk = blockIdx.x, tid = threadIdx.x;
    int lane = tid & 63, wv = tid >> 6;
    int rg = blk & 31, kq = (blk >> 5) & 1, h = blk >> 6;
    int r0 = rg * 8;
    __shared__ float x1[8][128];
#pragma unroll
    for (int pass = 0; pass < 2; ++pass) {
        int rr = wv + pass * 4;
        float xv = x[(r0 + rr) * CC + lane];
        float m = wred_sum(xv) * (1.f / CC);
        float d = xv - m;
        float var = wred_sum(d * d) * (1.f / CC);
        x1[rr][64 + lane] = d * rsqrtf(var + 1e-5f) * ln1g[lane] + ln1b[lane];
    }
    for (int e = tid; e < 512; e += 256) {
        int rr = e >> 6, cc = e & 63;
        int t = (r0 + rr) & (TT - 1);
        x1[rr][cc] = pos_p[t * CC + cc];
    }
    __syncthreads();
    const float* w = attW1 + (h * D4 + kq * 128) * D4;
    float acc[8] = {0, 0, 0, 0, 0, 0, 0, 0};
    for (int c = 0; c < 128; c++) {
        float wvv = w[c * D4 + tid];
#pragma unroll
        for (int rr = 0; rr < 8; rr++) acc[rr] += x1[rr][c] * wvv;
    }
    float badd = kq ? 0.f : ab1[h * D4 + tid];   // fold b1 into K
    float* outKQ = kq ? Qp : Kp;
#pragma unroll
    for (int rr = 0; rr < 8; rr++)               // pre-scale by log2e
        outKQ[(h * RR + r0 + rr) * D4 + tid] = (acc[rr] + badd) * LOG2E;
    if (kq == 0 && tid < 128) {
        int rr = tid >> 4, s = tid & 15;
        const float* wvw = valW + h * CC * SS;
        float a = 0.f;
        for (int k = 0; k < CC; k++) a += x1[rr][64 + k] * wvw[k * SS + s];
        v[(h * RR + r0 + rr) * SS + s] = a;
    }
}

// ============ scores: 16x16 causal tiles, thread = (i,j), no reduces =========
// grid = 4h x 2bat x 36 tiles = 288 blocks
__global__ void __launch_bounds__(256) k_score(
    const float* __restrict__ Kp, const float* __restrict__ Qp,
    const float* __restrict__ aw2, const float* __restrict__ ab2,
    float* __restrict__ scg) {
    int blk = blockIdx.x;
    int t = blk % 36, hb = blk / 36;
    int h = hb >> 1, bat = hb & 1;
    int ti = 0, a0 = 0;
    while (a0 + ti + 1 <= t) { a0 += ti + 1; ti++; }
    int tj = t - a0;
    int tid = threadIdx.x;
    int i = tid >> 4, j = tid & 15;
    __shared__ __align__(16) float qs[16][268], ks[16][268];   // pad: 2-way banks
    __shared__ __align__(16) float w2s[D4];
    const float* Qb = Qp + (size_t)(h * RR + bat * TT + ti * 16) * D4;
    const float* Kb = Kp + (size_t)(h * RR + bat * TT + tj * 16) * D4;
    for (int e = tid; e < 16 * 64; e += 256) {
        int r = e >> 6, c4 = (e & 63) * 4;
        *(float4*)&qs[r][c4] = *(const float4*)(Qb + r * D4 + c4);
        *(float4*)&ks[r][c4] = *(const float4*)(Kb + r * D4 + c4);
    }
    w2s[tid] = aw2[h * D4 + tid] * 0.125f;       // fold C^-0.5
    __syncthreads();
    float acc = 0.f;
#pragma unroll 4
    for (int dc = 0; dc < 64; ++dc) {
        float4 q4 = *(const float4*)&qs[i][dc * 4];
        float4 k4 = *(const float4*)&ks[j][dc * 4];
        float4 w4 = *(const float4*)&w2s[dc * 4];
        acc += sigm2(q4.x + k4.x) * w4.x + sigm2(q4.y + k4.y) * w4.y +
               sigm2(q4.z + k4.z) * w4.z + sigm2(q4.w + k4.w) * w4.w;
    }
    int ii = ti * 16 + i, jj = tj * 16 + j;
    float val = (jj <= ii) ? acc + ab2[h] * 0.125f : -1e30f;
    scg[((size_t)(h * 2 + bat) * TT + ii) * TT + jj] = val;
}

// ============ post: softmax+PV (per-head wave) + proj/FF/LNs ============
__global__ void __launch_bounds__(256) k_post(
    float* __restrict__ x, const float* __restrict__ scg,
    const float* __restrict__ v,
    const float* __restrict__ projW, const float* __restrict__ projb,
    const float* __restrict__ g2, const float* __restrict__ b2,
    const float* __restrict__ fW1, const float* __restrict__ fb1,
    const float* __restrict__ fW2, const float* __restrict__ fb2,
    const float* __restrict__ g3, const float* __restrict__ b3) {
    int row = blockIdx.x, tid = threadIdx.x;
    int lane = tid & 63, h = tid >> 6;
    int bat = row >> 7, i = row & 127;
    __shared__ float scn[HH][TT];
    __shared__ float o_s[CC], s_x[CC], s_h[HID_], red[4][CC];
    // softmax (wave h = head h)
    {
        const float* srow = scg + ((size_t)(h * 2 + bat) * TT + i) * TT;
        float s0 = (lane <= i) ? srow[lane] : -1e30f;
        float s1 = (lane + 64 <= i) ? srow[lane + 64] : -1e30f;
        float m = wred_max(fmaxf(s0, s1));
        float e0 = (lane <= i) ? __expf(s0 - m) : 0.f;
        float e1 = (lane + 64 <= i) ? __expf(s1 - m) : 0.f;
        float inv = __builtin_amdgcn_rcpf(wred_sum(e0 + e1));
        scn[h][lane] = e0 * inv;
        scn[h][lane + 64] = e1 * inv;
    }
    // PV (same wave wrote scn[h] -> in-wave ordering suffices)
    {
        int j4 = lane >> 4, s = lane & 15;
        const float* vb = v + (size_t)(h * RR + bat * TT) * SS;
        float acc = 0.f;
        for (int jj = j4; jj <= i; jj += 4) acc += scn[h][jj] * vb[jj * SS + s];
        acc += __shfl_xor(acc, 16, 64);
        acc += __shfl_xor(acc, 32, 64);
        if (j4 == 0) o_s[h * SS + s] = acc;
    }
    __syncthreads();
    {   // proj: 4-way k-split, 2 accumulators
        int c = tid & 63, q = tid >> 6;
        float a0 = 0.f, a1 = 0.f;
        int k0 = q * 16;
#pragma unroll
        for (int k = 0; k < 16; k += 2) {
            a0 += o_s[k0 + k] * projW[(k0 + k) * CC + c];
            a1 += o_s[k0 + k + 1] * projW[(k0 + k + 1) * CC + c];
        }
        red[q][c] = a0 + a1;
    }
    __syncthreads();
    float xv = 0.f;
    if (tid < CC) {
        xv = x[row * CC + tid] + projb[tid] +
             red[0][tid] + red[1][tid] + red[2][tid] + red[3][tid];
        float m = wred_sum(xv) * (1.f / CC);
        float d = xv - m;
        float var = wred_sum(d * d) * (1.f / CC);
        s_x[tid] = d * rsqrtf(var + 1e-5f) * g2[tid] + b2[tid];
    }
    __syncthreads();
    {   // FF1
        float a0 = fb1[tid], a1 = 0.f;
#pragma unroll
        for (int k = 0; k < CC; k += 2) {
            a0 += s_x[k] * fW1[k * HID_ + tid];
            a1 += s_x[k + 1] * fW1[(k + 1) * HID_ + tid];
        }
        s_h[tid] = sigm(a0 + a1);
    }
    __syncthreads();
    {   // FF2: 4-way k-split
        int c = tid & 63, q = tid >> 6;
        float a0 = 0.f, a1 = 0.f;
#pragma unroll
        for (int k = q * 64; k < q * 64 + 64; k += 2) {
            a0 += s_h[k] * fW2[k * CC + c];
            a1 += s_h[k + 1] * fW2[(k + 1) * CC + c];
        }
        red[q][c] = a0 + a1;
    }
    __syncthreads();
    if (tid < CC) {
        float f = fb2[tid] + red[0][tid] + red[1][tid] + red[2][tid] + red[3][tid];
        float x2 = xv + f;
        float m = wred_sum(x2) * (1.f / CC);
        float d = x2 - m;
        float var = wred_sum(d * d) * (1.f / CC);
        x[row * CC + tid] = d * rsqrtf(var + 1e-5f) * g3[tid] + b3[tid];
    }
}

// ============ lm_head: c-outer register GEMM ============
__global__ void __launch_bounds__(256, 4) k_lmhead(const float* __restrict__ x,
                                                   const float* __restrict__ lmW,
                                                   const float* __restrict__ lmb,
                                                   float* __restrict__ out) {
    int tid = threadIdx.x;
    int cp = tid & 127, rg = tid >> 7;
    int v2 = blockIdx.x * 256 + cp * 2;
    int r0 = blockIdx.y * 64;
    int rbase = rg * 32;
    __shared__ float xT[CC][68];            // transposed x tile, padded
    for (int e = tid; e < 64 * CC; e += 256) {
        int r = e >> 6, c = e & 63;
        xT[c][r] = x[(r0 + r) * CC + c];
    }
    __syncthreads();
    float2 bias = *(const float2*)(lmb + v2);
    float2 acc[32];
#pragma unroll
    for (int rr = 0; rr < 32; rr++) acc[rr] = bias;
    for (int c = 0; c < CC; ++c) {
        float2 w = *(const float2*)(lmW + (size_t)c * VV + v2);
#pragma unroll
        for (int q = 0; q < 8; ++q) {
            float4 xr = *(const float4*)&xT[c][rbase + q * 4];
            acc[q * 4 + 0].x += xr.x * w.x; acc[q * 4 + 0].y += xr.x * w.y;
            acc[q * 4 + 1].x += xr.y * w.x; acc[q * 4 + 1].y += xr.y * w.y;
            acc[q * 4 + 2].x += xr.z * w.x; acc[q * 4 + 2].y += xr.z * w.y;
            acc[q * 4 + 3].x += xr.w * w.x; acc[q * 4 + 3].y += xr.w * w.y;
        }
    }
#pragma unroll
    for (int rr = 0; rr < 32; rr++)
        *(float2*)(out + (size_t)(r0 + rbase + rr) * VV + v2) = acc[rr];
}

extern "C" void kernel_launch(void* const* d_in, const int* in_sizes, int n_in,
                              void* d_out, int out_size, void* d_ws, size_t ws_size,
                              hipStream_t stream) {
    const int*   idx   = (const int*)d_in[0];
    const float* tok   = (const float*)d_in[1];
    const float* petab = (const float*)d_in[2];
    const float* peW1  = (const float*)d_in[3];
    const float* peb1  = (const float*)d_in[4];
    const float* peW2  = (const float*)d_in[5];
    const float* peb2  = (const float*)d_in[6];
    const float* peg   = (const float*)d_in[7];
    const float* pebb  = (const float*)d_in[8];
    const float* ln1g  = (const float*)d_in[9];
    const float* ln1b  = (const float*)d_in[10];
    const float* attW1 = (const float*)d_in[11];
    const float* attb1 = (const float*)d_in[12];
    const float* attW2 = (const float*)d_in[13];
    const float* attb2 = (const float*)d_in[14];
    const float* valW  = (const float*)d_in[15];
    const float* projW = (const float*)d_in[16];
    const float* projb = (const float*)d_in[17];
    const float* ln2g  = (const float*)d_in[18];
    const float* ln2b  = (const float*)d_in[19];
    const float* ffW1  = (const float*)d_in[20];
    const float* ffb1  = (const float*)d_in[21];
    const float* ffW2  = (const float*)d_in[22];
    const float* ffb2  = (const float*)d_in[23];
    const float* ln3g  = (const float*)d_in[24];
    const float* ln3b  = (const float*)d_in[25];
    const float* lmW   = (const float*)d_in[26];
    const float* lmb   = (const float*)d_in[27];

    float* ws  = (float*)d_ws;
    float* x   = ws;                  // 16384
    float* pos = ws + 16384;          // 32768
    float* v   = ws + 49152;          // 16384
    float* Kp  = ws + 65536;          // 262144 (pre-scaled, +b1)
    float* Qp  = ws + 327680;         // 262144 (pre-scaled)
    float* scg = ws + 589824;         // 131072 (raw scores)

    k_embed_pos<<<768, CC, 0, stream>>>(idx, tok, petab, peW1, peb1, peW2, peb2,
                                        peg, pebb, x, pos);
    for (int p = 0; p < NPE_; p++) {
        k_stageA<<<256, 256, 0, stream>>>(x, pos + p * TT * CC, ln1g, ln1b,
                                          attW1, attb1, valW, Kp, Qp, v);
        k_score<<<288, 256, 0, stream>>>(Kp, Qp, attW2, attb2, scg);
        k_post<<<RR, 256, 0, stream>>>(x, scg, v, projW, projb, ln2g, ln2b,
                                       ffW1, ffb1, ffW2, ffb2, ln3g, ln3b);
    }
    k_lmhead<<<dim3(125, 4), 256, 0, stream>>>(x, lmW, lmb, (float*)d_out);
}